// Round 1
// baseline (79.146 us; speedup 1.0000x reference)
//
#include <hip/hip_runtime.h>

// 3x3 median filter, replicate border, float32, B x 2048 x 2048.
// One thread per float4 of output. Median-of-9 via triple-sort + med3 combine:
//   per row r: (lo,md,hi) = sorted horizontal triple
//   median9 = med3( max3(lo0,lo1,lo2), med3(md0,md1,md2), min3(hi0,hi1,hi2) )

#define MIN3(a,b,c) fminf(fminf((a),(b)),(c))
#define MAX3(a,b,c) fmaxf(fmaxf((a),(b)),(c))
#define MED3(a,b,c) __builtin_amdgcn_fmed3f((a),(b),(c))

__global__ __launch_bounds__(256) void median3x3_kernel(
    const float* __restrict__ in, float* __restrict__ out, int total4) {
    const int W = 2048, H = 2048;
    const int W4 = W / 4;          // 512
    int idx = blockIdx.x * blockDim.x + threadIdx.x;
    if (idx >= total4) return;

    int x4 = idx & (W4 - 1);           // [0, 512)
    int y  = (idx >> 9) & (H - 1);     // [0, 2048)
    int b  = idx >> 20;                // image index

    const float* img = in + (size_t)b * H * W;
    int x  = x4 << 2;
    int y0 = max(y - 1, 0);
    int y2 = min(y + 1, H - 1);
    int xl = max(x - 1, 0);
    int xr = min(x + 4, W - 1);

    float lo[3][4], md[3][4], hi[3][4];
    int ys[3] = { y0, y, y2 };

    #pragma unroll
    for (int r = 0; r < 3; ++r) {
        const float* row = img + (size_t)ys[r] * W;
        float4 v = *reinterpret_cast<const float4*>(row + x);
        float e0 = row[xl];
        float e5 = row[xr];
        float e[6] = { e0, v.x, v.y, v.z, v.w, e5 };
        #pragma unroll
        for (int j = 0; j < 4; ++j) {
            float a = e[j], bb = e[j + 1], c = e[j + 2];
            lo[r][j] = MIN3(a, bb, c);
            md[r][j] = MED3(a, bb, c);
            hi[r][j] = MAX3(a, bb, c);
        }
    }

    float res[4];
    #pragma unroll
    for (int j = 0; j < 4; ++j) {
        float mx = MAX3(lo[0][j], lo[1][j], lo[2][j]);
        float me = MED3(md[0][j], md[1][j], md[2][j]);
        float mn = MIN3(hi[0][j], hi[1][j], hi[2][j]);
        res[j] = MED3(mx, me, mn);
    }

    float4 o;
    o.x = res[0]; o.y = res[1]; o.z = res[2]; o.w = res[3];
    *reinterpret_cast<float4*>(out + (size_t)idx * 4) = o;
}

extern "C" void kernel_launch(void* const* d_in, const int* in_sizes, int n_in,
                              void* d_out, int out_size, void* d_ws, size_t ws_size,
                              hipStream_t stream) {
    const float* x = (const float*)d_in[0];
    float* out = (float*)d_out;

    const int H = 2048, W = 2048;
    int B = in_sizes[0] / (H * W);          // 8
    int total4 = B * H * (W / 4);           // 8,388,608 threads
    int block = 256;
    int grid = (total4 + block - 1) / block; // 32768 blocks

    median3x3_kernel<<<grid, block, 0, stream>>>(x, out, total4);
}

// Round 2
// 47.970 us; speedup vs baseline: 1.6499x; 1.6499x over previous
//
#include <hip/hip_runtime.h>

// 3x3 median, replicate border, float32, 8 x 2048 x 2048.
// Each thread: a 4-wide x 8-tall column strip. Loads 10 rows (float4 each),
// computes per-row sorted horizontal triples (lo, md, hi) once, keeps a
// 3-slot ring, emits 8 outputs:
//   median9 = med3( max3(lo0,lo1,lo2), med3(md0,md1,md2), min3(hi0,hi1,hi2) )
// Horizontal halo via wave shuffles; lanes 0/63 fix up with a masked load.

#define MIN3(a,b,c) fminf(fminf((a),(b)),(c))
#define MAX3(a,b,c) fmaxf(fmaxf((a),(b)),(c))
#define MED3(a,b,c) __builtin_amdgcn_fmed3f((a),(b),(c))

constexpr int W  = 2048;
constexpr int H  = 2048;
constexpr int W4 = W / 4;        // 512
constexpr int R  = 8;            // output rows per thread
constexpr int TY = H / R;        // 256 tiles vertically

__global__ __launch_bounds__(256) void median3x3_kernel(
    const float* __restrict__ in, float* __restrict__ out, int nblocks) {
    // Bijective XCD-aware chunked swizzle (nblocks % 8 == 0):
    // vertically adjacent tiles share halo rows -> keep them on one XCD's L2.
    int b   = blockIdx.x;
    int cpx = nblocks >> 3;
    int swz = (b & 7) * cpx + (b >> 3);
    int idx = swz * 256 + (int)threadIdx.x;

    int x4    = idx & (W4 - 1);          // 9 bits
    int yt    = (idx >> 9) & (TY - 1);   // 8 bits
    int img_i = idx >> 17;               // [0, 8)

    const float* img  = in  + (size_t)img_i * H * W;
    float*       oimg = out + (size_t)img_i * H * W;

    int lane = (int)threadIdx.x & 63;
    int x    = x4 << 2;
    int y0   = yt * R;

    float lo[3][4], md[3][4], hi[3][4];

    #pragma unroll
    for (int i = 0; i < R + 2; ++i) {
        int yi = y0 - 1 + i;
        yi = max(0, min(H - 1, yi));
        const float* row = img + (size_t)yi * W;
        float4 v = *reinterpret_cast<const float4*>(row + x);

        // horizontal halo from neighbor lanes; fix wave-boundary lanes
        float e0 = __shfl_up(v.w, 1);
        float e5 = __shfl_down(v.x, 1);
        if (lane == 0)  e0 = (x4 == 0)      ? v.x : row[x - 1];
        if (lane == 63) e5 = (x4 == W4 - 1) ? v.w : row[x + 4];

        float e[6] = { e0, v.x, v.y, v.z, v.w, e5 };
        const int s = i % 3;   // compile-time constant after full unroll
        #pragma unroll
        for (int j = 0; j < 4; ++j) {
            float a = e[j], bb = e[j + 1], c = e[j + 2];
            lo[s][j] = MIN3(a, bb, c);
            md[s][j] = MED3(a, bb, c);
            hi[s][j] = MAX3(a, bb, c);
        }

        if (i >= 2) {
            float res[4];
            #pragma unroll
            for (int j = 0; j < 4; ++j) {
                float mx = MAX3(lo[0][j], lo[1][j], lo[2][j]);
                float me = MED3(md[0][j], md[1][j], md[2][j]);
                float mn = MIN3(hi[0][j], hi[1][j], hi[2][j]);
                res[j] = MED3(mx, me, mn);   // row-permutation invariant
            }
            float4 o;
            o.x = res[0]; o.y = res[1]; o.z = res[2]; o.w = res[3];
            *reinterpret_cast<float4*>(oimg + (size_t)(y0 + i - 2) * W + x) = o;
        }
    }
}

extern "C" void kernel_launch(void* const* d_in, const int* in_sizes, int n_in,
                              void* d_out, int out_size, void* d_ws, size_t ws_size,
                              hipStream_t stream) {
    const float* x = (const float*)d_in[0];
    float* outp = (float*)d_out;

    int B = in_sizes[0] / (H * W);                 // 8
    int total = B * TY * W4;                       // 1,048,576 threads
    int block = 256;
    int grid  = total / block;                     // 4096 blocks (% 8 == 0)

    median3x3_kernel<<<grid, block, 0, stream>>>(x, outp, grid);
}

// Round 4
// 46.791 us; speedup vs baseline: 1.6915x; 1.0252x over previous
//
#include <hip/hip_runtime.h>

// 3x3 median, replicate border, float32, 8 x 2048 x 2048.
// Each thread: a 4-wide x 16-tall column strip. Loads 18 rows (float4 each),
// computes per-row sorted horizontal triples (lo, md, hi) once, keeps a
// 3-slot ring, emits 16 outputs via
//   median9 = med3( max3(lo0,lo1,lo2), med3(md0,md1,md2), min3(hi0,hi1,hi2) )
// Horizontal halo via wave shuffles (lanes 0/63 fix up with a masked load).
// Output stored non-temporally (native ext_vector type — HIP_vector_type
// doesn't satisfy __builtin_nontemporal_store) to keep input L3-resident.

#define MIN3(a,b,c) fminf(fminf((a),(b)),(c))
#define MAX3(a,b,c) fmaxf(fmaxf((a),(b)),(c))
#define MED3(a,b,c) __builtin_amdgcn_fmed3f((a),(b),(c))

typedef float nfloat4 __attribute__((ext_vector_type(4)));

constexpr int W  = 2048;
constexpr int H  = 2048;
constexpr int W4 = W / 4;        // 512
constexpr int R  = 16;           // output rows per thread
constexpr int TY = H / R;        // 128 tiles vertically

__global__ __launch_bounds__(256) void median3x3_kernel(
    const float* __restrict__ in, float* __restrict__ out, int nblocks) {
    // Bijective XCD-aware chunked swizzle (nblocks % 8 == 0):
    // vertically adjacent tiles share halo rows -> keep them on one XCD's L2.
    int b   = blockIdx.x;
    int cpx = nblocks >> 3;
    int swz = (b & 7) * cpx + (b >> 3);
    int idx = swz * 256 + (int)threadIdx.x;

    int x4    = idx & (W4 - 1);          // 9 bits
    int yt    = (idx >> 9) & (TY - 1);   // 7 bits
    int img_i = idx >> 16;               // [0, 8)

    const float* img  = in  + (size_t)img_i * H * W;
    float*       oimg = out + (size_t)img_i * H * W;

    int lane = (int)threadIdx.x & 63;
    int x    = x4 << 2;
    int y0   = yt * R;

    float lo[3][4], md[3][4], hi[3][4];

    #pragma unroll
    for (int i = 0; i < R + 2; ++i) {
        int yi = y0 - 1 + i;
        yi = max(0, min(H - 1, yi));
        const float* row = img + (size_t)yi * W;
        nfloat4 v = *reinterpret_cast<const nfloat4*>(row + x);

        // horizontal halo from neighbor lanes; fix wave-boundary lanes
        float e0 = __shfl_up(v.w, 1);
        float e5 = __shfl_down(v.x, 1);
        if (lane == 0)  e0 = (x4 == 0)      ? v.x : row[x - 1];
        if (lane == 63) e5 = (x4 == W4 - 1) ? v.w : row[x + 4];

        float e[6] = { e0, v.x, v.y, v.z, v.w, e5 };
        const int s = i % 3;   // compile-time constant after full unroll
        #pragma unroll
        for (int j = 0; j < 4; ++j) {
            float a = e[j], bb = e[j + 1], c = e[j + 2];
            lo[s][j] = MIN3(a, bb, c);
            md[s][j] = MED3(a, bb, c);
            hi[s][j] = MAX3(a, bb, c);
        }

        if (i >= 2) {
            nfloat4 o;
            #pragma unroll
            for (int j = 0; j < 4; ++j) {
                float mx = MAX3(lo[0][j], lo[1][j], lo[2][j]);
                float me = MED3(md[0][j], md[1][j], md[2][j]);
                float mn = MIN3(hi[0][j], hi[1][j], hi[2][j]);
                o[j] = MED3(mx, me, mn);   // row-permutation invariant
            }
            __builtin_nontemporal_store(
                o, reinterpret_cast<nfloat4*>(oimg + (size_t)(y0 + i - 2) * W + x));
        }
    }
}

extern "C" void kernel_launch(void* const* d_in, const int* in_sizes, int n_in,
                              void* d_out, int out_size, void* d_ws, size_t ws_size,
                              hipStream_t stream) {
    const float* x = (const float*)d_in[0];
    float* outp = (float*)d_out;

    int B = in_sizes[0] / (H * W);                 // 8
    int total = B * TY * W4;                       // 524,288 threads
    int block = 256;
    int grid  = total / block;                     // 2048 blocks (% 8 == 0)

    median3x3_kernel<<<grid, block, 0, stream>>>(x, outp, grid);
}